// Round 2
// baseline (909.167 us; speedup 1.0000x reference)
//
#include <hip/hip_runtime.h>
#include <hip/hip_bf16.h>
#include <math.h>

// Problem constants
#define BB 2
#define CC 64
#define HH 256
#define WW 256
#define OO 64
#define KK 3
#define K2 9
#define HW (HH*WW)          // 65536
#define CHW (CC*HW)

// ws layout (floats):
//  wt   [576*27]   : combined offset+amp conv weights, transposed [s][27]
//  wt3  [576*64]   : w3d transposed [s][o]
//  ys   [B*9*HW]
//  xs   [B*9*HW]
//  av   [B*9*HW]
#define WT_OFF   0
#define WT3_OFF  (576*27)                 // 15552
#define YS_OFF   (WT3_OFF + 576*64)       // 52416
#define XS_OFF   (YS_OFF + BB*K2*HW)
#define AV_OFF   (XS_OFF + BB*K2*HW)

// Bijective XCD swizzle: nwg divisible by 8. Blocks with the same final
// work-id neighborhood run on the same XCD -> shared input rows stay in L2.
__device__ __forceinline__ int xcd_swz(int bid, int nwg) {
    const int per = nwg >> 3;
    return (bid & 7) * per + (bid >> 3);
}

__global__ __launch_bounds__(256) void k_prep(
    const float* __restrict__ offw, const float* __restrict__ ampw,
    const float* __restrict__ w3d, float* __restrict__ wt, float* __restrict__ wt3)
{
    int i = blockIdx.x * 256 + threadIdx.x;
    const int total = 576*27 + 576*64;
    for (; i < total; i += gridDim.x * 256) {
        if (i < 576*27) {
            int s = i / 27, ch = i % 27;
            wt[i] = (ch < 18) ? offw[ch*576 + s] : ampw[(ch-18)*576 + s];
        } else {
            int j = i - 576*27;
            int s = j >> 6, o = j & 63;
            wt3[j] = w3d[o*576 + s];
        }
    }
}

// Kernel 1: offset conv (18 ch) + amp conv (9 ch), thread per output pixel.
// Weights staged in LDS (broadcast reads), XCD-swizzled blocks.
__global__ __launch_bounds__(256) void k_offsets(
    const float* __restrict__ x, const float* __restrict__ wt,
    const float* __restrict__ offb, const float* __restrict__ ampb,
    float* __restrict__ ys, float* __restrict__ xs, float* __restrict__ av)
{
    __shared__ float wlo[576*27];   // 62208 B
    const int tid = threadIdx.x;
    for (int i = tid; i < 576*27; i += 256) wlo[i] = wt[i];
    __syncthreads();

    const int bh = xcd_swz(blockIdx.x, BB*HH);
    const int h = bh & 255;
    const int b = bh >> 8;
    const int w = tid;

    float acc[27];
#pragma unroll
    for (int i = 0; i < 27; ++i) acc[i] = 0.f;

    const float* xb = x + (size_t)b * CHW;
    for (int c = 0; c < CC; ++c) {
        const float* xc = xb + c * HW;
#pragma unroll
        for (int ky = 0; ky < 3; ++ky) {
            const int iy = h + ky - 1;
            const bool rowok = (unsigned)iy < 256u;
            const float* xr = xc + iy * WW;
#pragma unroll
            for (int kx = 0; kx < 3; ++kx) {
                const int ix = w + kx - 1;
                const float v = (rowok && (unsigned)ix < 256u) ? xr[ix] : 0.f;
                const float* wr = &wlo[(c*9 + ky*3 + kx)*27];
#pragma unroll
                for (int ch = 0; ch < 27; ++ch)
                    acc[ch] = fmaf(v, wr[ch], acc[ch]);
            }
        }
    }

    const int pix = h * WW + w;
    const size_t base = (size_t)b * K2 * HW;
#pragma unroll
    for (int k = 0; k < K2; ++k) {
        const float yoff = acc[2*k]     + offb[2*k];
        const float xoff = acc[2*k + 1] + offb[2*k + 1];
        const int ky = k / 3, kx = k % 3;
        float yy = (float)(h + ky) + yoff;
        float xx = (float)(w + kx) + xoff;
        yy = fminf(fmaxf(yy, 0.f), 257.f);
        xx = fminf(fmaxf(xx, 0.f), 257.f);
        float aa = acc[18 + k] + ampb[k];
        aa = 1.f / (1.f + expf(-aa));
        ys[base + k*HW + pix] = yy;
        xs[base + k*HW + pix] = xx;
        av[base + k*HW + pix] = aa;
    }
}

// Kernel 2: bilinear sampling + modulation + [576 x 64] contraction + ReLU.
// One block per (b,h); ALL 64 o computed (no duplicated gathers).
// Weights staged per-k-slice: 16 KB LDS -> high occupancy.
__global__ __launch_bounds__(256, 4) void k_main(
    const float* __restrict__ x, const float* __restrict__ wt3,
    const float* __restrict__ ys, const float* __restrict__ xs,
    const float* __restrict__ av, float* __restrict__ out)
{
    __shared__ float wl[64 * 64];   // [c][o] for current k, 16384 B
    const int tid = threadIdx.x;
    const int bh = xcd_swz(blockIdx.x, BB*HH);
    const int h = bh & 255;
    const int b = bh >> 8;

    float acc[64];
#pragma unroll
    for (int i = 0; i < 64; ++i) acc[i] = 0.f;

    const int w = tid;
    const float* xb = x + (size_t)b * CHW;
    size_t sb = (size_t)b * K2 * HW + h * WW + w;

    const float4* wt3_4 = (const float4*)wt3;
    float4* wl4 = (float4*)wl;

    for (int k = 0; k < K2; ++k) {
        // stage weights for this k-slice: wl[c*64+o] = wt3[(c*9+k)*64+o]
        if (k) __syncthreads();      // previous iteration done reading wl
#pragma unroll
        for (int t = 0; t < 4; ++t) {
            const int j = tid + t*256;          // j in [0,1024): c = j>>4, q = j&15
            wl4[j] = wt3_4[((j >> 4)*9 + k)*16 + (j & 15)];
        }
        __syncthreads();

        const float yy = ys[sb];
        const float xx = xs[sb];
        const float aa = av[sb];
        sb += HW;

        const float y0f = floorf(yy), x0f = floorf(xx);
        const float y1f = fminf(y0f + 1.f, 257.f);
        const float x1f = fminf(x0f + 1.f, 257.f);
        const float ay = yy - y0f, by = y1f - yy;
        const float ax = xx - x0f, bx = x1f - xx;

        const int r0 = (int)y0f - 1, r1 = (int)y1f - 1;
        const int c0 = (int)x0f - 1, c1 = (int)x1f - 1;
        const bool vy0 = (unsigned)r0 < 256u, vy1 = (unsigned)r1 < 256u;
        const bool vx0 = (unsigned)c0 < 256u, vx1 = (unsigned)c1 < 256u;

        float w00 = by*bx*aa, w01 = by*ax*aa, w10 = ay*bx*aa, w11 = ay*ax*aa;
        int o00, o01, o10, o11;
        if (vy0 && vx0) o00 = r0*WW + c0; else { o00 = 0; w00 = 0.f; }
        if (vy0 && vx1) o01 = r0*WW + c1; else { o01 = 0; w01 = 0.f; }
        if (vy1 && vx0) o10 = r1*WW + c0; else { o10 = 0; w10 = 0.f; }
        if (vy1 && vx1) o11 = r1*WW + c1; else { o11 = 0; w11 = 0.f; }

        const float* pc = xb;
#pragma unroll 2
        for (int c = 0; c < CC; ++c) {
            const float v = w00*pc[o00] + w01*pc[o01] + w10*pc[o10] + w11*pc[o11];
            pc += HW;
            const float4* wr = (const float4*)&wl[c << 6];
#pragma unroll
            for (int j = 0; j < 16; ++j) {
                const float4 wv = wr[j];
                acc[4*j + 0] = fmaf(v, wv.x, acc[4*j + 0]);
                acc[4*j + 1] = fmaf(v, wv.y, acc[4*j + 1]);
                acc[4*j + 2] = fmaf(v, wv.z, acc[4*j + 2]);
                acc[4*j + 3] = fmaf(v, wv.w, acc[4*j + 3]);
            }
        }
    }

    const size_t ob = (size_t)b * OO * HW + h * WW + w;
#pragma unroll
    for (int j = 0; j < 64; ++j)
        out[ob + (size_t)j * HW] = fmaxf(acc[j], 0.f);
}

extern "C" void kernel_launch(void* const* d_in, const int* in_sizes, int n_in,
                              void* d_out, int out_size, void* d_ws, size_t ws_size,
                              hipStream_t stream) {
    const float* x    = (const float*)d_in[0];
    const float* offw = (const float*)d_in[1];
    const float* offb = (const float*)d_in[2];
    const float* ampw = (const float*)d_in[3];
    const float* ampb = (const float*)d_in[4];
    const float* w3d  = (const float*)d_in[5];
    float* out = (float*)d_out;
    float* ws  = (float*)d_ws;

    float* wt  = ws + WT_OFF;
    float* wt3 = ws + WT3_OFF;
    float* ys  = ws + YS_OFF;
    float* xs  = ws + XS_OFF;
    float* av  = ws + AV_OFF;

    k_prep<<<64, 256, 0, stream>>>(offw, ampw, w3d, wt, wt3);
    k_offsets<<<BB*HH, 256, 0, stream>>>(x, wt, offb, ampb, ys, xs, av);
    k_main<<<BB*HH, 256, 0, stream>>>(x, wt3, ys, xs, av, out);
}

// Round 3
// 365.654 us; speedup vs baseline: 2.4864x; 2.4864x over previous
//
#include <hip/hip_runtime.h>
#include <hip/hip_bf16.h>
#include <math.h>

// Problem constants
#define BB 2
#define CC 64
#define HH 256
#define WW 256
#define OO 64
#define K2 9
#define HW (HH*WW)          // 65536
#define CHW (CC*HW)

// ws layout (floats):
//  wt [15552]            : combined offset+amp conv weights, transposed [s][27]
//  wk [20736 floats]     : w3d as bf16 [k][o][72] (72 = 64 c + 8 pad), ushort
//  ys/xs/av [B*9*HW] each
#define WT_OFF   0
#define WK_OFF   15552
#define YS_OFF   (WK_OFF + 20736)
#define XS_OFF   (YS_OFF + BB*K2*HW)
#define AV_OFF   (XS_OFF + BB*K2*HW)

typedef __attribute__((ext_vector_type(8))) short sh8;
typedef __attribute__((ext_vector_type(4))) float f32x4;

// Bijective XCD swizzle (nwg divisible by 8): consecutive final ids share an XCD.
__device__ __forceinline__ int xcd_swz(int bid, int nwg) {
    const int per = nwg >> 3;
    return (bid & 7) * per + (bid >> 3);
}

__global__ __launch_bounds__(256) void k_prep(
    const float* __restrict__ offw, const float* __restrict__ ampw,
    const float* __restrict__ w3d, float* __restrict__ wt,
    unsigned short* __restrict__ wk)
{
    int i = blockIdx.x * 256 + threadIdx.x;
    const int total = 15552 + 9*64*72;
    for (; i < total; i += gridDim.x * 256) {
        if (i < 15552) {
            int s = i / 27, ch = i % 27;
            wt[i] = (ch < 18) ? offw[ch*576 + s] : ampw[(ch-18)*576 + s];
        } else {
            int j = i - 15552;
            int k = j / 4608, rem = j % 4608;
            int o = rem / 72, c = rem % 72;
            float v = (c < 64) ? w3d[o*576 + c*9 + k] : 0.f;
            __hip_bfloat16 hb = __float2bfloat16(v);
            wk[j] = *(unsigned short*)&hb;
        }
    }
}

// Kernel 1: offset conv (18 ch) + amp conv (9 ch), thread per output pixel.
// Weights staged in LDS (broadcast reads), XCD-swizzled blocks. (unchanged R2)
__global__ __launch_bounds__(256) void k_offsets(
    const float* __restrict__ x, const float* __restrict__ wt,
    const float* __restrict__ offb, const float* __restrict__ ampb,
    float* __restrict__ ys, float* __restrict__ xs, float* __restrict__ av)
{
    __shared__ float wlo[576*27];   // 62208 B
    const int tid = threadIdx.x;
    for (int i = tid; i < 576*27; i += 256) wlo[i] = wt[i];
    __syncthreads();

    const int bh = xcd_swz(blockIdx.x, BB*HH);
    const int h = bh & 255;
    const int b = bh >> 8;
    const int w = tid;

    float acc[27];
#pragma unroll
    for (int i = 0; i < 27; ++i) acc[i] = 0.f;

    const float* xb = x + (size_t)b * CHW;
    for (int c = 0; c < CC; ++c) {
        const float* xc = xb + c * HW;
#pragma unroll
        for (int ky = 0; ky < 3; ++ky) {
            const int iy = h + ky - 1;
            const bool rowok = (unsigned)iy < 256u;
            const float* xr = xc + iy * WW;
#pragma unroll
            for (int kx = 0; kx < 3; ++kx) {
                const int ix = w + kx - 1;
                const float v = (rowok && (unsigned)ix < 256u) ? xr[ix] : 0.f;
                const float* wr = &wlo[(c*9 + ky*3 + kx)*27];
#pragma unroll
                for (int ch = 0; ch < 27; ++ch)
                    acc[ch] = fmaf(v, wr[ch], acc[ch]);
            }
        }
    }

    const int pix = h * WW + w;
    const size_t base = (size_t)b * K2 * HW;
#pragma unroll
    for (int k = 0; k < K2; ++k) {
        const float yoff = acc[2*k]     + offb[2*k];
        const float xoff = acc[2*k + 1] + offb[2*k + 1];
        const int ky = k / 3, kx = k % 3;
        float yy = (float)(h + ky) + yoff;
        float xx = (float)(w + kx) + xoff;
        yy = fminf(fmaxf(yy, 0.f), 257.f);
        xx = fminf(fmaxf(xx, 0.f), 257.f);
        float aa = acc[18 + k] + ampb[k];
        aa = 1.f / (1.f + expf(-aa));
        ys[base + k*HW + pix] = yy;
        xs[base + k*HW + pix] = xx;
        av[base + k*HW + pix] = aa;
    }
}

// Kernel 2: bilinear sampling into LDS (bf16) + MFMA contraction + ReLU.
// Block = 256 threads = 4 waves, owns 64 pixels (quarter row) x all 64 o.
// Per k (9): stage val[64p][64c] bf16 + w[64o][64c] bf16, then 8 MFMA/wave.
__global__ __launch_bounds__(256, 4) void k_main(
    const float* __restrict__ x, const unsigned short* __restrict__ wk,
    const float* __restrict__ ys, const float* __restrict__ xs,
    const float* __restrict__ av, float* __restrict__ out)
{
    // val rows: 144 B stride (72 bf16: 64 used + pad). 16B-aligned, 36 dw = 4 mod 32.
    __shared__ __attribute__((aligned(16))) unsigned char lds[18432];
    unsigned char* aB = lds;            // val[64][72] bf16
    unsigned char* bB = lds + 9216;     // wb [64][72] bf16

    const int tid = threadIdx.x;
    const int idx = xcd_swz(blockIdx.x, BB*HH*4);
    const int wq = idx & 3;
    const int h  = (idx >> 2) & 255;
    const int b  = idx >> 10;
    const int w0 = wq << 6;

    const int p    = tid & 63;     // pixel within tile (also lane)
    const int cq   = tid >> 6;     // c-quarter for staging (also wave id)
    const int lane = tid & 63;
    const int wv   = tid >> 6;
    const int lrow = lane & 15;
    const int lg   = lane >> 4;

    f32x4 acc[4];
#pragma unroll
    for (int n = 0; n < 4; ++n) acc[n] = (f32x4){0.f, 0.f, 0.f, 0.f};

    const float* xb = x + (size_t)b * CHW;
    const float* pcBase = xb + (size_t)(cq * 16) * HW;
    const size_t sb = (size_t)b * K2 * HW + h * WW + w0 + p;

    for (int k = 0; k < K2; ++k) {
        if (k) __syncthreads();    // prev MFMA done before overwrite

        // stage weights for this k: 576 x 16B linear copy
        {
            const uint4* src = (const uint4*)(wk + (size_t)k * 4608);
            uint4* dst = (uint4*)bB;
            dst[tid]       = src[tid];
            dst[tid + 256] = src[tid + 256];
            if (tid < 64) dst[tid + 512] = src[tid + 512];
        }

        // stage val: thread = (pixel p, c-quarter cq)
        {
            const float yy = ys[sb + (size_t)k * HW];
            const float xx = xs[sb + (size_t)k * HW];
            const float aa = av[sb + (size_t)k * HW];

            const float y0f = floorf(yy), x0f = floorf(xx);
            const float y1f = fminf(y0f + 1.f, 257.f);
            const float x1f = fminf(x0f + 1.f, 257.f);
            const float ay = yy - y0f, by = y1f - yy;
            const float ax = xx - x0f, bx = x1f - xx;

            const int r0 = (int)y0f - 1, r1 = (int)y1f - 1;
            const int c0 = (int)x0f - 1, c1 = (int)x1f - 1;
            const bool vy0 = (unsigned)r0 < 256u, vy1 = (unsigned)r1 < 256u;
            const bool vx0 = (unsigned)c0 < 256u, vx1 = (unsigned)c1 < 256u;

            float w00 = by*bx*aa, w01 = by*ax*aa, w10 = ay*bx*aa, w11 = ay*ax*aa;
            int o00, o01, o10, o11;
            if (vy0 && vx0) o00 = r0*WW + c0; else { o00 = 0; w00 = 0.f; }
            if (vy0 && vx1) o01 = r0*WW + c1; else { o01 = 0; w01 = 0.f; }
            if (vy1 && vx0) o10 = r1*WW + c0; else { o10 = 0; w10 = 0.f; }
            if (vy1 && vx1) o11 = r1*WW + c1; else { o11 = 0; w11 = 0.f; }

            union { unsigned short us[16]; uint4 q[2]; } buf;
            const float* pc = pcBase;
#pragma unroll
            for (int ci = 0; ci < 16; ++ci) {
                const float v = w00*pc[o00] + w01*pc[o01] + w10*pc[o10] + w11*pc[o11];
                __hip_bfloat16 hb = __float2bfloat16(v);
                buf.us[ci] = *(unsigned short*)&hb;
                pc += HW;
            }
            uint4* vd = (uint4*)(aB + p*144 + cq*32);
            vd[0] = buf.q[0];
            vd[1] = buf.q[1];
        }
        __syncthreads();

        // MFMA: wave wv owns pixels [wv*16, wv*16+16), all 64 o, K=64 (2 steps)
#pragma unroll
        for (int kk = 0; kk < 2; ++kk) {
            const sh8 a = *(const sh8*)(aB + (wv*16 + lrow)*144 + lg*16 + kk*64);
#pragma unroll
            for (int n = 0; n < 4; ++n) {
                const sh8 bb = *(const sh8*)(bB + (n*16 + lrow)*144 + lg*16 + kk*64);
                acc[n] = __builtin_amdgcn_mfma_f32_16x16x32_bf16(a, bb, acc[n], 0, 0, 0);
            }
        }
    }

    // Epilogue: transpose via LDS -> coalesced stores + ReLU
    __syncthreads();
    float* ct = (float*)lds;   // [64 o][65]
#pragma unroll
    for (int n = 0; n < 4; ++n)
#pragma unroll
        for (int r = 0; r < 4; ++r)
            ct[(n*16 + lrow)*65 + wv*16 + lg*4 + r] = acc[n][r];
    __syncthreads();

    const size_t ob = (size_t)b * OO * HW + h * WW + w0;
#pragma unroll
    for (int it = 0; it < 16; ++it) {
        const int o = it*4 + wv;
        out[ob + (size_t)o * HW + lane] = fmaxf(ct[o*65 + lane], 0.f);
    }
}

extern "C" void kernel_launch(void* const* d_in, const int* in_sizes, int n_in,
                              void* d_out, int out_size, void* d_ws, size_t ws_size,
                              hipStream_t stream) {
    const float* x    = (const float*)d_in[0];
    const float* offw = (const float*)d_in[1];
    const float* offb = (const float*)d_in[2];
    const float* ampw = (const float*)d_in[3];
    const float* ampb = (const float*)d_in[4];
    const float* w3d  = (const float*)d_in[5];
    float* out = (float*)d_out;
    float* ws  = (float*)d_ws;

    float* wt = ws + WT_OFF;
    unsigned short* wkp = (unsigned short*)(ws + WK_OFF);
    float* ys = ws + YS_OFF;
    float* xs = ws + XS_OFF;
    float* av = ws + AV_OFF;

    k_prep<<<64, 256, 0, stream>>>(offw, ampw, w3d, wt, wkp);
    k_offsets<<<BB*HH, 256, 0, stream>>>(x, wt, offb, ampb, ys, xs, av);
    k_main<<<BB*HH*4, 256, 0, stream>>>(x, wkp, ys, xs, av, out);
}

// Round 4
// 182.532 us; speedup vs baseline: 4.9809x; 2.0032x over previous
//
#include <hip/hip_runtime.h>
#include <hip/hip_bf16.h>
#include <math.h>

// Problem constants
#define BB 2
#define CC 64
#define HH 256
#define WW 256
#define OO 64
#define K2 9
#define HW 65536
#define CHW (CC*HW)

typedef __attribute__((ext_vector_type(8))) short sh8;
typedef __attribute__((ext_vector_type(8))) unsigned short ush8;
typedef __attribute__((ext_vector_type(4))) float f32x4;

// Bijective XCD swizzle (nwg divisible by 8)
__device__ __forceinline__ int xcd_swz(int bid, int nwg) {
    const int per = nwg >> 3;
    return (bid & 7) * per + (bid >> 3);
}
__device__ __forceinline__ float b2f(unsigned short u) {
    unsigned int x = ((unsigned int)u) << 16;
    return __builtin_bit_cast(float, x);
}
__device__ __forceinline__ unsigned short f2b(float f) {
    __hip_bfloat16 h = __float2bfloat16(f);
    return __builtin_bit_cast(unsigned short, h);
}

// wA: [32 ch][576 s'] bf16, s' = tap*64 + c (tap-major K order). rows 27..31 = 0.
// wk: [9 k][64 o][64 c] bf16.
__global__ __launch_bounds__(256) void k_prep(
    const float* __restrict__ offw, const float* __restrict__ ampw,
    const float* __restrict__ w3d,
    unsigned short* __restrict__ wA, unsigned short* __restrict__ wk)
{
    int i = blockIdx.x * 256 + threadIdx.x;   // grid 216 -> 55296 exact
    if (i < 18432) {
        int ch = i / 576, sp = i % 576;
        int tap = sp >> 6, c = sp & 63;
        float v = 0.f;
        if (ch < 18)      v = offw[ch*576 + c*9 + tap];
        else if (ch < 27) v = ampw[(ch-18)*576 + c*9 + tap];
        wA[i] = f2b(v);
    } else if (i < 55296) {
        int j = i - 18432;
        int k = j >> 12, rem = j & 4095;
        int o = rem >> 6, c = rem & 63;
        wk[j] = f2b(w3d[o*576 + c*9 + k]);
    }
}

// Fused: tile staging -> offset/amp conv (MFMA) -> deformable sampling (LDS
// bilerp, global fallback) -> [64px x 576] x [576 x 64o] MFMA -> ReLU store.
// Block = 256 thr = 4 waves, owns (b, h, 64-px quarter-row), all 64 o.
__global__ __launch_bounds__(256, 2) void k_fused(
    const float* __restrict__ x, const unsigned short* __restrict__ wA,
    const unsigned short* __restrict__ wk,
    const float* __restrict__ offb, const float* __restrict__ ampb,
    float* __restrict__ out)
{
    // LDS map:
    //  tb  [0,43520)      : tile bf16, 340 planes (pp = rrel*68+ccrel) x 128B (64 c),
    //                       c-slot XOR-swizzled by (pp&7)
    //  aB  [43520,51712)  : A val[64 px][64 c] bf16, XOR-swizzled
    //  bB  [51712,59904)  : B  w [64 o ][64 c] bf16, XOR-swizzled
    //  ot16[59904,63576)  : conv+bias out bf16 [27 ch][68]
    __shared__ __attribute__((aligned(16))) unsigned char lds[63584];
    unsigned char* tb = lds;
    unsigned char* aB = lds + 43520;
    unsigned char* bB = lds + 51712;
    unsigned short* ot16 = (unsigned short*)(lds + 59904);

    const int tid = threadIdx.x;
    const int idx = xcd_swz(blockIdx.x, BB*HH*4);
    const int wq = idx & 3, h = (idx >> 2) & 255, b = idx >> 10;
    const int w0 = wq << 6;
    const int lane = tid & 63, wv = tid >> 6;
    const int lrow = lane & 15, lg = lane >> 4;
    const int p = lane, cq = wv;

    const float* xb = x + (size_t)b * CHW;

    // ---- Phase 1: stage tile (abs rows h-2..h+2, cols w0-2..w0+65, 0 outside image)
    {
        const int r0a = h - 2, c0a = w0 - 2;
        int c = 0, rem = tid;               // f = c*340 + rem, rem = rr*68+cc
        for (int i = 0; i < 85; ++i) {
            int rr = rem / 68;
            int cc = rem - rr*68;
            int ra = r0a + rr, ca = c0a + cc;
            float v = 0.f;
            if ((unsigned)ra < 256u && (unsigned)ca < 256u)
                v = xb[c*HW + ra*256 + ca];
            int byte = rem*128 + ((2*c) ^ ((rem & 7) << 4));
            *(unsigned short*)(tb + byte) = f2b(v);
            rem += 256;
            if (rem >= 340) { rem -= 340; ++c; }
        }
    }
    __syncthreads();

    // ---- Phase 2: offset/amp conv via MFMA. D[m=ch(32)][n=px(16/wave)], K=576.
    {
        f32x4 oacc0 = {0.f,0.f,0.f,0.f}, oacc1 = {0.f,0.f,0.f,0.f};
        const int pxl = wv*16 + lrow;
        for (int ks = 0; ks < 18; ++ks) {
            const int sbase = ks*32 + lg*8;
            const int tap = sbase >> 6;
            const int cb  = sbase & 63;
            const int ky = tap / 3, kx = tap - ky*3;
            const int pp = (ky + 1)*68 + pxl + kx + 1;
            const sh8 bf = *(const sh8*)(tb + pp*128 + ((2*cb) ^ ((pp & 7) << 4)));
            const sh8 a0 = *(const sh8*)(wA + (      lrow)*576 + sbase);
            const sh8 a1 = *(const sh8*)(wA + (16 + lrow)*576 + sbase);
            oacc0 = __builtin_amdgcn_mfma_f32_16x16x32_bf16(a0, bf, oacc0, 0, 0, 0);
            oacc1 = __builtin_amdgcn_mfma_f32_16x16x32_bf16(a1, bf, oacc1, 0, 0, 0);
        }
        // write conv+bias to persistent ot16[ch][68]
#pragma unroll
        for (int r = 0; r < 4; ++r) {
            int ch0 = lg*4 + r;                         // 0..15
            ot16[ch0*68 + pxl] = f2b(oacc0[r] + offb[ch0]);
            int ch1 = 16 + lg*4 + r;                    // 16..31
            if (ch1 < 27) {
                float bias = (ch1 < 18) ? offb[ch1] : ampb[ch1 - 18];
                ot16[ch1*68 + pxl] = f2b(oacc1[r] + bias);
            }
        }
    }
    __syncthreads();

    // ---- Phase 3: main K-loop over 9 taps
    f32x4 acc[4];
#pragma unroll
    for (int n = 0; n < 4; ++n) acc[n] = (f32x4){0.f, 0.f, 0.f, 0.f};

    const int swA = (p & 7) << 4;     // A-write swizzle (row p)
    const int swF = (lrow & 7) << 4;  // fragment-read swizzle

    for (int k = 0; k < K2; ++k) {
        if (k) __syncthreads();

        // stage bB from wk[k] (XOR-swizzled [64 o][64 c])
        {
            const uint4* src = (const uint4*)(wk + (size_t)k * 4096);
#pragma unroll
            for (int t = 0; t < 2; ++t) {
                int j = tid + t*256;                    // 0..511
                int row = j >> 3, colq = j & 7;
                uint4 v = src[j];
                *(uint4*)(bB + row*128 + ((colq*16) ^ ((row & 7) << 4))) = v;
            }
        }

        // per-pixel sampling params for this tap
        const int ky = k / 3, kx = k - ky*3;
        const float oy = b2f(ot16[(2*k  )*68 + p]);
        const float ox = b2f(ot16[(2*k+1)*68 + p]);
        const float az = b2f(ot16[(18+k )*68 + p]);
        float yy = (float)(h + ky) + oy;
        float xx = (float)(w0 + p + kx) + ox;
        yy = fminf(fmaxf(yy, 0.f), 257.f);
        xx = fminf(fmaxf(xx, 0.f), 257.f);
        const float aa = 1.f / (1.f + expf(-az));

        const float y0f = floorf(yy), x0f = floorf(xx);
        const float y1f = fminf(y0f + 1.f, 257.f);
        const float x1f = fminf(x0f + 1.f, 257.f);
        const float ay = yy - y0f, by = y1f - yy;
        const float ax = xx - x0f, bx = x1f - xx;
        const int r0 = (int)y0f - 1, r1 = (int)y1f - 1;
        const int c0 = (int)x0f - 1, c1 = (int)x1f - 1;
        const int rr0 = r0 - (h - 2), rr1 = r1 - (h - 2);
        const int cc0 = c0 - (w0 - 2), cc1 = c1 - (w0 - 2);
        float w00 = by*bx*aa, w01 = by*ax*aa, w10 = ay*bx*aa, w11 = ay*ax*aa;

        union { unsigned short us[16]; uint4 q[2]; } buf;
        const bool ok = ((unsigned)rr0 <= 4u) && ((unsigned)rr1 <= 4u) &&
                        ((unsigned)cc0 <= 67u) && ((unsigned)cc1 <= 67u);
        if (ok) {
            // fast path: 8 x ds_read_b128 (4 corners x 16 c), tile has pad zeros
            const int pp00 = rr0*68 + cc0, pp01 = rr0*68 + cc1;
            const int pp10 = rr1*68 + cc0, pp11 = rr1*68 + cc1;
            const int cb0 = cq*32, cb1 = cq*32 + 16;
            const ush8 v00a = *(const ush8*)(tb + pp00*128 + (cb0 ^ ((pp00&7)<<4)));
            const ush8 v00b = *(const ush8*)(tb + pp00*128 + (cb1 ^ ((pp00&7)<<4)));
            const ush8 v01a = *(const ush8*)(tb + pp01*128 + (cb0 ^ ((pp01&7)<<4)));
            const ush8 v01b = *(const ush8*)(tb + pp01*128 + (cb1 ^ ((pp01&7)<<4)));
            const ush8 v10a = *(const ush8*)(tb + pp10*128 + (cb0 ^ ((pp10&7)<<4)));
            const ush8 v10b = *(const ush8*)(tb + pp10*128 + (cb1 ^ ((pp10&7)<<4)));
            const ush8 v11a = *(const ush8*)(tb + pp11*128 + (cb0 ^ ((pp11&7)<<4)));
            const ush8 v11b = *(const ush8*)(tb + pp11*128 + (cb1 ^ ((pp11&7)<<4)));
#pragma unroll
            for (int ci = 0; ci < 8; ++ci) {
                float v = w00*b2f(v00a[ci]) + w01*b2f(v01a[ci]) +
                          w10*b2f(v10a[ci]) + w11*b2f(v11a[ci]);
                buf.us[ci] = f2b(v);
            }
#pragma unroll
            for (int ci = 0; ci < 8; ++ci) {
                float v = w00*b2f(v00b[ci]) + w01*b2f(v01b[ci]) +
                          w10*b2f(v10b[ci]) + w11*b2f(v11b[ci]);
                buf.us[8 + ci] = f2b(v);
            }
        } else {
            // slow path (rare): global gathers with border zeroing
            const bool vy0 = (unsigned)r0 < 256u, vy1 = (unsigned)r1 < 256u;
            const bool vx0 = (unsigned)c0 < 256u, vx1 = (unsigned)c1 < 256u;
            float W00 = w00, W01 = w01, W10 = w10, W11 = w11;
            int o00, o01, o10, o11;
            if (vy0 && vx0) o00 = r0*WW + c0; else { o00 = 0; W00 = 0.f; }
            if (vy0 && vx1) o01 = r0*WW + c1; else { o01 = 0; W01 = 0.f; }
            if (vy1 && vx0) o10 = r1*WW + c0; else { o10 = 0; W10 = 0.f; }
            if (vy1 && vx1) o11 = r1*WW + c1; else { o11 = 0; W11 = 0.f; }
            const float* pc = xb + (size_t)(cq*16) * HW;
#pragma unroll
            for (int ci = 0; ci < 16; ++ci) {
                float v = W00*pc[o00] + W01*pc[o01] + W10*pc[o10] + W11*pc[o11];
                pc += HW;
                buf.us[ci] = f2b(v);
            }
        }
        *(uint4*)(aB + p*128 + ((cq*32     ) ^ swA)) = buf.q[0];
        *(uint4*)(aB + p*128 + ((cq*32 + 16) ^ swA)) = buf.q[1];

        __syncthreads();

        // MFMA: wave wv owns px rows [wv*16, wv*16+16), all 64 o, K=64
#pragma unroll
        for (int kk = 0; kk < 2; ++kk) {
            const sh8 afr = *(const sh8*)(aB + (wv*16 + lrow)*128 +
                                          ((lg*16 + kk*64) ^ swF));
#pragma unroll
            for (int n = 0; n < 4; ++n) {
                const sh8 bfr = *(const sh8*)(bB + (n*16 + lrow)*128 +
                                              ((lg*16 + kk*64) ^ swF));
                acc[n] = __builtin_amdgcn_mfma_f32_16x16x32_bf16(afr, bfr, acc[n], 0, 0, 0);
            }
        }
    }

    // ---- Epilogue: transpose via LDS (overlays tile) -> coalesced ReLU stores
    __syncthreads();
    float* ct = (float*)lds;    // [64 o][66]
#pragma unroll
    for (int n = 0; n < 4; ++n)
#pragma unroll
        for (int r = 0; r < 4; ++r)
            ct[(n*16 + lrow)*66 + wv*16 + lg*4 + r] = acc[n][r];
    __syncthreads();

    const size_t ob = (size_t)b*OO*HW + (size_t)h*WW + w0;
#pragma unroll
    for (int it = 0; it < 16; ++it) {
        int o = it*4 + wv;
        out[ob + (size_t)o*HW + lane] = fmaxf(ct[o*66 + lane], 0.f);
    }
}

extern "C" void kernel_launch(void* const* d_in, const int* in_sizes, int n_in,
                              void* d_out, int out_size, void* d_ws, size_t ws_size,
                              hipStream_t stream) {
    const float* x    = (const float*)d_in[0];
    const float* offw = (const float*)d_in[1];
    const float* offb = (const float*)d_in[2];
    const float* ampw = (const float*)d_in[3];
    const float* ampb = (const float*)d_in[4];
    const float* w3d  = (const float*)d_in[5];
    float* out = (float*)d_out;

    unsigned short* wA = (unsigned short*)d_ws;          // 18432 bf16
    unsigned short* wk = wA + 18432;                     // 36864 bf16

    k_prep<<<216, 256, 0, stream>>>(offw, ampw, w3d, wA, wk);
    k_fused<<<BB*HH*4, 256, 0, stream>>>(x, wA, wk, offb, ampb, out);
}

// Round 5
// 166.804 us; speedup vs baseline: 5.4505x; 1.0943x over previous
//
#include <hip/hip_runtime.h>
#include <hip/hip_bf16.h>
#include <math.h>

// Problem constants
#define BB 2
#define CC 64
#define HH 256
#define WW 256
#define OO 64
#define K2 9
#define HW 65536
#define CHW (CC*HW)

typedef __attribute__((ext_vector_type(8))) short sh8;
typedef __attribute__((ext_vector_type(8))) unsigned short ush8;
typedef __attribute__((ext_vector_type(4))) float f32x4;

// Bijective XCD swizzle (nwg divisible by 8)
__device__ __forceinline__ int xcd_swz(int bid, int nwg) {
    const int per = nwg >> 3;
    return (bid & 7) * per + (bid >> 3);
}
__device__ __forceinline__ float b2f(unsigned short u) {
    unsigned int x = ((unsigned int)u) << 16;
    return __builtin_bit_cast(float, x);
}
__device__ __forceinline__ unsigned short f2b(float f) {
    __hip_bfloat16 h = __float2bfloat16(f);
    return __builtin_bit_cast(unsigned short, h);
}

// wA: [32 ch][576 s'] bf16, s' = tap*64 + c (tap-major K order). rows 27..31 = 0.
// wk: [9 k][64 o][64 c] bf16.
__global__ __launch_bounds__(256) void k_prep(
    const float* __restrict__ offw, const float* __restrict__ ampw,
    const float* __restrict__ w3d,
    unsigned short* __restrict__ wA, unsigned short* __restrict__ wk)
{
    int i = blockIdx.x * 256 + threadIdx.x;   // grid 216 -> 55296 exact
    if (i < 18432) {
        int ch = i / 576, sp = i % 576;
        int tap = sp >> 6, c = sp & 63;
        float v = 0.f;
        if (ch < 18)      v = offw[ch*576 + c*9 + tap];
        else if (ch < 27) v = ampw[(ch-18)*576 + c*9 + tap];
        wA[i] = f2b(v);
    } else if (i < 55296) {
        int j = i - 18432;
        int k = j >> 12, rem = j & 4095;
        int o = rem >> 6, c = rem & 63;
        wk[j] = f2b(w3d[o*576 + c*9 + k]);
    }
}

// Fused kernel. Block = 256 thr = 4 waves, owns (b, h, 64-px quarter-row), all 64 o.
// Pipeline: tile stage -> offset/amp conv (MFMA) -> per-tap {B-frags from global,
// sample(k+1) from LDS tile, MFMA(k), write aB[next], ONE barrier}.
__global__ __launch_bounds__(256, 2) void k_fused(
    const float* __restrict__ x, const unsigned short* __restrict__ wA,
    const unsigned short* __restrict__ wk,
    const float* __restrict__ offb, const float* __restrict__ ampb,
    float* __restrict__ out)
{
    // LDS map:
    //  tb  [0,43520)      : tile bf16, 340 planes (pp = rrel*68+ccrel) x 128B (64 c),
    //                       16B-slot XOR-swizzled by (pp&7)
    //  aB0 [43520,51712)  : A val[64 px][64 c] bf16 (even taps), XOR-swizzled
    //  aB1 [51712,59904)  : A val buffer (odd taps)
    //  ot16[59904,63576)  : conv+bias out bf16 [27 ch][68]
    __shared__ __attribute__((aligned(16))) unsigned char lds[63584];
    unsigned char* tb  = lds;
    unsigned char* aB0 = lds + 43520;
    unsigned char* aB1 = lds + 51712;
    unsigned short* ot16 = (unsigned short*)(lds + 59904);

    const int tid = threadIdx.x;
    const int idx = xcd_swz(blockIdx.x, BB*HH*4);
    const int wq = idx & 3, h = (idx >> 2) & 255, b = idx >> 10;
    const int w0 = wq << 6;
    const int lane = tid & 63, wv = tid >> 6;
    const int lrow = lane & 15, lg = lane >> 4;
    const int p = lane, cq = wv;

    const float* xb = x + (size_t)b * CHW;

    // ---- Phase 1: stage tile (abs rows h-2..h+2, cols w0-2..w0+65, 0 outside),
    // c-pairs packed into ds_write_b32.
    {
        const int r0a = h - 2, c0a = w0 - 2;
        int q = 0, rem = tid;              // j = q*340 + rem, rem = rr*68+cc
        for (int i = 0; i < 43; ++i) {
            if (i < 42 || tid < 128) {
                int rr = rem / 68;
                int cc = rem - rr*68;
                int ra = r0a + rr, ca = c0a + cc;
                float v0 = 0.f, v1 = 0.f;
                if ((unsigned)ra < 256u && (unsigned)ca < 256u) {
                    const float* px = xb + (size_t)(2*q)*HW + ra*256 + ca;
                    v0 = px[0];
                    v1 = px[HW];
                }
                unsigned int pk = (unsigned int)f2b(v0) | ((unsigned int)f2b(v1) << 16);
                *(unsigned int*)(tb + rem*128 + ((4*q) ^ ((rem & 7) << 4))) = pk;
            }
            rem += 256;
            if (rem >= 340) { rem -= 340; ++q; }
        }
    }
    __syncthreads();

    // ---- Phase 2: offset/amp conv via MFMA. D[m=ch(32)][n=px(16/wave)], K=576.
    {
        f32x4 oacc0 = {0.f,0.f,0.f,0.f}, oacc1 = {0.f,0.f,0.f,0.f};
        const int pxl = wv*16 + lrow;
        for (int ks = 0; ks < 18; ++ks) {
            const int sbase = ks*32 + lg*8;
            const int tap = sbase >> 6;
            const int cb  = sbase & 63;
            const int ky = tap / 3, kx = tap - ky*3;
            const int pp = (ky + 1)*68 + pxl + kx + 1;
            const sh8 bf = *(const sh8*)(tb + pp*128 + ((2*cb) ^ ((pp & 7) << 4)));
            const sh8 a0 = *(const sh8*)(wA + (      lrow)*576 + sbase);
            const sh8 a1 = *(const sh8*)(wA + (16 + lrow)*576 + sbase);
            oacc0 = __builtin_amdgcn_mfma_f32_16x16x32_bf16(a0, bf, oacc0, 0, 0, 0);
            oacc1 = __builtin_amdgcn_mfma_f32_16x16x32_bf16(a1, bf, oacc1, 0, 0, 0);
        }
#pragma unroll
        for (int r = 0; r < 4; ++r) {
            int ch0 = lg*4 + r;
            ot16[ch0*68 + pxl] = f2b(oacc0[r] + offb[ch0]);
            int ch1 = 16 + lg*4 + r;
            if (ch1 < 27) {
                float bias = (ch1 < 18) ? offb[ch1] : ampb[ch1 - 18];
                ot16[ch1*68 + pxl] = f2b(oacc1[r] + bias);
            }
        }
    }
    __syncthreads();

    // ---- Sampling helper: tap kt -> 16 bf16 c-values (this thread's c-quarter)
    const int swA = (p & 7) << 4;     // A-write swizzle (row p)
    const int swF = (lrow & 7) << 4;  // fragment-read swizzle

    auto sample_tap = [&](int kt, uint4& q0, uint4& q1) {
        const int ky = kt / 3, kx = kt - ky*3;
        const float oy = b2f(ot16[(2*kt  )*68 + p]);
        const float ox = b2f(ot16[(2*kt+1)*68 + p]);
        const float az = b2f(ot16[(18+kt )*68 + p]);
        float yy = (float)(h + ky) + oy;
        float xx = (float)(w0 + p + kx) + ox;
        yy = fminf(fmaxf(yy, 0.f), 257.f);
        xx = fminf(fmaxf(xx, 0.f), 257.f);
        const float aa = 1.f / (1.f + expf(-az));

        const float y0f = floorf(yy), x0f = floorf(xx);
        const float y1f = fminf(y0f + 1.f, 257.f);
        const float x1f = fminf(x0f + 1.f, 257.f);
        const float ay = yy - y0f, by = y1f - yy;
        const float ax = xx - x0f, bx = x1f - xx;
        const int r0 = (int)y0f - 1, r1 = (int)y1f - 1;
        const int c0 = (int)x0f - 1, c1 = (int)x1f - 1;
        const int rr0 = r0 - (h - 2), rr1 = r1 - (h - 2);
        const int cc0 = c0 - (w0 - 2), cc1 = c1 - (w0 - 2);
        float w00 = by*bx*aa, w01 = by*ax*aa, w10 = ay*bx*aa, w11 = ay*ax*aa;

        union { unsigned short us[16]; uint4 q[2]; } buf;
        const bool ok = ((unsigned)rr0 <= 4u) && ((unsigned)rr1 <= 4u) &&
                        ((unsigned)cc0 <= 67u) && ((unsigned)cc1 <= 67u);
        if (ok) {
            const int pp00 = rr0*68 + cc0, pp01 = rr0*68 + cc1;
            const int pp10 = rr1*68 + cc0, pp11 = rr1*68 + cc1;
            const int cb0 = cq*32, cb1 = cq*32 + 16;
            const ush8 v00a = *(const ush8*)(tb + pp00*128 + (cb0 ^ ((pp00&7)<<4)));
            const ush8 v00b = *(const ush8*)(tb + pp00*128 + (cb1 ^ ((pp00&7)<<4)));
            const ush8 v01a = *(const ush8*)(tb + pp01*128 + (cb0 ^ ((pp01&7)<<4)));
            const ush8 v01b = *(const ush8*)(tb + pp01*128 + (cb1 ^ ((pp01&7)<<4)));
            const ush8 v10a = *(const ush8*)(tb + pp10*128 + (cb0 ^ ((pp10&7)<<4)));
            const ush8 v10b = *(const ush8*)(tb + pp10*128 + (cb1 ^ ((pp10&7)<<4)));
            const ush8 v11a = *(const ush8*)(tb + pp11*128 + (cb0 ^ ((pp11&7)<<4)));
            const ush8 v11b = *(const ush8*)(tb + pp11*128 + (cb1 ^ ((pp11&7)<<4)));
#pragma unroll
            for (int ci = 0; ci < 8; ++ci) {
                float v = w00*b2f(v00a[ci]) + w01*b2f(v01a[ci]) +
                          w10*b2f(v10a[ci]) + w11*b2f(v11a[ci]);
                buf.us[ci] = f2b(v);
            }
#pragma unroll
            for (int ci = 0; ci < 8; ++ci) {
                float v = w00*b2f(v00b[ci]) + w01*b2f(v01b[ci]) +
                          w10*b2f(v10b[ci]) + w11*b2f(v11b[ci]);
                buf.us[8 + ci] = f2b(v);
            }
        } else {
            const bool vy0 = (unsigned)r0 < 256u, vy1 = (unsigned)r1 < 256u;
            const bool vx0 = (unsigned)c0 < 256u, vx1 = (unsigned)c1 < 256u;
            float W00 = w00, W01 = w01, W10 = w10, W11 = w11;
            int o00, o01, o10, o11;
            if (vy0 && vx0) o00 = r0*WW + c0; else { o00 = 0; W00 = 0.f; }
            if (vy0 && vx1) o01 = r0*WW + c1; else { o01 = 0; W01 = 0.f; }
            if (vy1 && vx0) o10 = r1*WW + c0; else { o10 = 0; W10 = 0.f; }
            if (vy1 && vx1) o11 = r1*WW + c1; else { o11 = 0; W11 = 0.f; }
            const float* pc = xb + (size_t)(cq*16) * HW;
#pragma unroll
            for (int ci = 0; ci < 16; ++ci) {
                float v = W00*pc[o00] + W01*pc[o01] + W10*pc[o10] + W11*pc[o11];
                pc += HW;
                buf.us[ci] = f2b(v);
            }
        }
        q0 = buf.q[0];
        q1 = buf.q[1];
    };

    // ---- Phase 3: software-pipelined K-loop, ONE barrier per tap
    f32x4 acc[4];
#pragma unroll
    for (int n = 0; n < 4; ++n) acc[n] = (f32x4){0.f, 0.f, 0.f, 0.f};

    // prologue: sample tap 0 into aB0
    {
        uint4 q0, q1;
        sample_tap(0, q0, q1);
        *(uint4*)(aB0 + p*128 + ((cq*32     ) ^ swA)) = q0;
        *(uint4*)(aB0 + p*128 + ((cq*32 + 16) ^ swA)) = q1;
    }
    __syncthreads();

    for (int k = 0; k < K2; ++k) {
        unsigned char* aCur = (k & 1) ? aB1 : aB0;
        unsigned char* aNxt = (k & 1) ? aB0 : aB1;

        // B-fragments for tap k, directly from global (L2-resident 8KB slice)
        sh8 bf0[4], bf1[4];
        {
            const unsigned short* wb = wk + (size_t)k*4096 + lg*8;
#pragma unroll
            for (int n = 0; n < 4; ++n) {
                bf0[n] = *(const sh8*)(wb + (n*16 + lrow)*64);
                bf1[n] = *(const sh8*)(wb + (n*16 + lrow)*64 + 32);
            }
        }

        // sample next tap while B loads are in flight
        uint4 q0, q1;
        const bool more = (k + 1) < K2;
        if (more) sample_tap(k + 1, q0, q1);

        // MFMA tap k
#pragma unroll
        for (int kk = 0; kk < 2; ++kk) {
            const sh8 afr = *(const sh8*)(aCur + (wv*16 + lrow)*128 +
                                          ((lg*16 + kk*64) ^ swF));
#pragma unroll
            for (int n = 0; n < 4; ++n)
                acc[n] = __builtin_amdgcn_mfma_f32_16x16x32_bf16(
                    afr, kk ? bf1[n] : bf0[n], acc[n], 0, 0, 0);
        }

        if (more) {
            *(uint4*)(aNxt + p*128 + ((cq*32     ) ^ swA)) = q0;
            *(uint4*)(aNxt + p*128 + ((cq*32 + 16) ^ swA)) = q1;
            __syncthreads();
        }
    }

    // ---- Epilogue: transpose via LDS (overlays tile) -> coalesced ReLU stores
    float* ct = (float*)lds;    // [64 o][66]
#pragma unroll
    for (int n = 0; n < 4; ++n)
#pragma unroll
        for (int r = 0; r < 4; ++r)
            ct[(n*16 + lrow)*66 + wv*16 + lg*4 + r] = acc[n][r];
    __syncthreads();

    const size_t ob = (size_t)b*OO*HW + (size_t)h*WW + w0;
#pragma unroll
    for (int it = 0; it < 16; ++it) {
        int o = it*4 + wv;
        out[ob + (size_t)o*HW + lane] = fmaxf(ct[o*66 + lane], 0.f);
    }
}

extern "C" void kernel_launch(void* const* d_in, const int* in_sizes, int n_in,
                              void* d_out, int out_size, void* d_ws, size_t ws_size,
                              hipStream_t stream) {
    const float* x    = (const float*)d_in[0];
    const float* offw = (const float*)d_in[1];
    const float* offb = (const float*)d_in[2];
    const float* ampw = (const float*)d_in[3];
    const float* ampb = (const float*)d_in[4];
    const float* w3d  = (const float*)d_in[5];
    float* out = (float*)d_out;

    unsigned short* wA = (unsigned short*)d_ws;          // 18432 bf16
    unsigned short* wk = wA + 18432;                     // 36864 bf16

    k_prep<<<216, 256, 0, stream>>>(offw, ampw, w3d, wA, wk);
    k_fused<<<BB*HH*4, 256, 0, stream>>>(x, wA, wk, offb, ampb, out);
}

// Round 6
// 152.819 us; speedup vs baseline: 5.9493x; 1.0915x over previous
//
#include <hip/hip_runtime.h>
#include <hip/hip_bf16.h>
#include <math.h>

// Problem constants
#define BB 2
#define CC 64
#define HH 256
#define WW 256
#define OO 64
#define K2 9
#define HW 65536
#define CHW (CC*HW)

typedef __attribute__((ext_vector_type(8))) short sh8;
typedef __attribute__((ext_vector_type(8))) unsigned short ush8;
typedef __attribute__((ext_vector_type(4))) float f32x4;

// Bijective XCD swizzle (nwg divisible by 8)
__device__ __forceinline__ int xcd_swz(int bid, int nwg) {
    const int per = nwg >> 3;
    return (bid & 7) * per + (bid >> 3);
}
__device__ __forceinline__ float b2f(unsigned short u) {
    unsigned int x = ((unsigned int)u) << 16;
    return __builtin_bit_cast(float, x);
}
__device__ __forceinline__ unsigned short f2b(float f) {
    __hip_bfloat16 h = __float2bfloat16(f);
    return __builtin_bit_cast(unsigned short, h);
}

// wA: [32 ch][576 s'] bf16, s' = tap*64 + c (tap-major K order). rows 27..31 = 0.
// wk: [9 k][64 o][64 c] bf16.
__global__ __launch_bounds__(256) void k_prep(
    const float* __restrict__ offw, const float* __restrict__ ampw,
    const float* __restrict__ w3d,
    unsigned short* __restrict__ wA, unsigned short* __restrict__ wk)
{
    int i = blockIdx.x * 256 + threadIdx.x;   // grid 216 -> 55296 exact
    if (i < 18432) {
        int ch = i / 576, sp = i % 576;
        int tap = sp >> 6, c = sp & 63;
        float v = 0.f;
        if (ch < 18)      v = offw[ch*576 + c*9 + tap];
        else if (ch < 27) v = ampw[(ch-18)*576 + c*9 + tap];
        wA[i] = f2b(v);
    } else if (i < 55296) {
        int j = i - 18432;
        int k = j >> 12, rem = j & 4095;
        int o = rem >> 6, c = rem & 63;
        wk[j] = f2b(w3d[o*576 + c*9 + k]);
    }
}

// Fused kernel. Block = 256 thr = 4 waves, owns (b, h, 64-px quarter-row), all 64 o.
// Key idea: thread (lrow, lg) samples exactly ITS OWN MFMA A-fragment c-values
// (c = kk*32 + lg*8 + [0,8)) for pixel px = wv*16+lrow -> no aB LDS buffer,
// no k-loop barriers; waves free-run across taps.
__global__ __launch_bounds__(256, 3) void k_fused(
    const float* __restrict__ x, const unsigned short* __restrict__ wA,
    const unsigned short* __restrict__ wk,
    const float* __restrict__ offb, const float* __restrict__ ampb,
    float* __restrict__ out)
{
    // LDS map:
    //  tb  [0,43520)      : tile bf16, 340 planes (pp = rrel*68+ccrel) x 128B (64 c),
    //                       16B-slot XOR-swizzled by (pp&7)
    //  ot16[43520,47192)  : conv+bias out bf16 [27 ch][68]
    //  epilogue: ct f32 [64][66] overlays tb.
    __shared__ __attribute__((aligned(16))) unsigned char lds[47200];
    unsigned char* tb = lds;
    unsigned short* ot16 = (unsigned short*)(lds + 43520);

    const int tid = threadIdx.x;
    const int idx = xcd_swz(blockIdx.x, BB*HH*4);
    const int wq = idx & 3, h = (idx >> 2) & 255, b = idx >> 10;
    const int w0 = wq << 6;
    const int lane = tid & 63, wv = tid >> 6;
    const int lrow = lane & 15, lg = lane >> 4;

    const float* xb = x + (size_t)b * CHW;

    // ---- Phase 1: stage tile (abs rows h-2..h+2, cols w0-2..w0+65, 0 outside),
    // c-pairs packed into ds_write_b32.
    {
        const int r0a = h - 2, c0a = w0 - 2;
        int q = 0, rem = tid;              // j = q*340 + rem, rem = rr*68+cc
        for (int i = 0; i < 43; ++i) {
            if (i < 42 || tid < 128) {
                int rr = rem / 68;
                int cc = rem - rr*68;
                int ra = r0a + rr, ca = c0a + cc;
                float v0 = 0.f, v1 = 0.f;
                if ((unsigned)ra < 256u && (unsigned)ca < 256u) {
                    const float* px = xb + (size_t)(2*q)*HW + ra*256 + ca;
                    v0 = px[0];
                    v1 = px[HW];
                }
                unsigned int pk = (unsigned int)f2b(v0) | ((unsigned int)f2b(v1) << 16);
                *(unsigned int*)(tb + rem*128 + ((4*q) ^ ((rem & 7) << 4))) = pk;
            }
            rem += 256;
            if (rem >= 340) { rem -= 340; ++q; }
        }
    }
    __syncthreads();

    // ---- Phase 2: offset/amp conv via MFMA. D[m=ch(32)][n=px(16/wave)], K=576.
    {
        f32x4 oacc0 = {0.f,0.f,0.f,0.f}, oacc1 = {0.f,0.f,0.f,0.f};
        const int pxl = wv*16 + lrow;
        for (int ks = 0; ks < 18; ++ks) {
            const int sbase = ks*32 + lg*8;
            const int tap = sbase >> 6;
            const int cb  = sbase & 63;
            const int ky = tap / 3, kx = tap - ky*3;
            const int pp = (ky + 1)*68 + pxl + kx + 1;
            const sh8 bf = *(const sh8*)(tb + pp*128 + ((2*cb) ^ ((pp & 7) << 4)));
            const sh8 a0 = *(const sh8*)(wA + (      lrow)*576 + sbase);
            const sh8 a1 = *(const sh8*)(wA + (16 + lrow)*576 + sbase);
            oacc0 = __builtin_amdgcn_mfma_f32_16x16x32_bf16(a0, bf, oacc0, 0, 0, 0);
            oacc1 = __builtin_amdgcn_mfma_f32_16x16x32_bf16(a1, bf, oacc1, 0, 0, 0);
        }
#pragma unroll
        for (int r = 0; r < 4; ++r) {
            int ch0 = lg*4 + r;
            ot16[ch0*68 + pxl] = f2b(oacc0[r] + offb[ch0]);
            int ch1 = 16 + lg*4 + r;
            if (ch1 < 27) {
                float bias = (ch1 < 18) ? offb[ch1] : ampb[ch1 - 18];
                ot16[ch1*68 + pxl] = f2b(oacc1[r] + bias);
            }
        }
    }
    __syncthreads();

    // ---- Phase 3: barrier-free K-loop over 9 taps.
    f32x4 acc[4];
#pragma unroll
    for (int n = 0; n < 4; ++n) acc[n] = (f32x4){0.f, 0.f, 0.f, 0.f};

    const int px = wv*16 + lrow;          // this thread's A-row pixel
    const int cA0 = lg*8;                 // kk=0 c-chunk base
    const int cA1 = 32 + lg*8;            // kk=1 c-chunk base
    const int cb0 = lg*16;                // byte offsets within a 128B plane
    const int cb1 = 64 + lg*16;

    for (int k = 0; k < K2; ++k) {
        // B-fragments for tap k, directly from global (L2-resident 8KB slice)
        sh8 bf0[4], bf1[4];
        {
            const unsigned short* wb = wk + (size_t)k*4096 + lg*8;
#pragma unroll
            for (int n = 0; n < 4; ++n) {
                bf0[n] = *(const sh8*)(wb + (n*16 + lrow)*64);
                bf1[n] = *(const sh8*)(wb + (n*16 + lrow)*64 + 32);
            }
        }

        // sampling params for (px, tap k)
        const int ky = k / 3, kx = k - ky*3;
        const float oy = b2f(ot16[(2*k  )*68 + px]);
        const float ox = b2f(ot16[(2*k+1)*68 + px]);
        const float az = b2f(ot16[(18+k )*68 + px]);
        float yy = (float)(h + ky) + oy;
        float xx = (float)(w0 + px + kx) + ox;
        yy = fminf(fmaxf(yy, 0.f), 257.f);
        xx = fminf(fmaxf(xx, 0.f), 257.f);
        const float aa = 1.f / (1.f + expf(-az));

        const float y0f = floorf(yy), x0f = floorf(xx);
        const float y1f = fminf(y0f + 1.f, 257.f);
        const float x1f = fminf(x0f + 1.f, 257.f);
        const float ay = yy - y0f, by = y1f - yy;
        const float ax = xx - x0f, bx = x1f - xx;
        const int r0 = (int)y0f - 1, r1 = (int)y1f - 1;
        const int c0 = (int)x0f - 1, c1 = (int)x1f - 1;
        const int rr0 = r0 - (h - 2), rr1 = r1 - (h - 2);
        const int cc0 = c0 - (w0 - 2), cc1 = c1 - (w0 - 2);
        float w00 = by*bx*aa, w01 = by*ax*aa, w10 = ay*bx*aa, w11 = ay*ax*aa;

        sh8 a0, a1;    // this thread's A-fragments (kk=0, kk=1)
        const bool ok = ((unsigned)rr0 <= 4u) && ((unsigned)rr1 <= 4u) &&
                        ((unsigned)cc0 <= 67u) && ((unsigned)cc1 <= 67u);
        if (ok) {
            const int pp00 = rr0*68 + cc0, pp01 = rr0*68 + cc1;
            const int pp10 = rr1*68 + cc0, pp11 = rr1*68 + cc1;
            const ush8 v00a = *(const ush8*)(tb + pp00*128 + (cb0 ^ ((pp00&7)<<4)));
            const ush8 v01a = *(const ush8*)(tb + pp01*128 + (cb0 ^ ((pp01&7)<<4)));
            const ush8 v10a = *(const ush8*)(tb + pp10*128 + (cb0 ^ ((pp10&7)<<4)));
            const ush8 v11a = *(const ush8*)(tb + pp11*128 + (cb0 ^ ((pp11&7)<<4)));
            const ush8 v00b = *(const ush8*)(tb + pp00*128 + (cb1 ^ ((pp00&7)<<4)));
            const ush8 v01b = *(const ush8*)(tb + pp01*128 + (cb1 ^ ((pp01&7)<<4)));
            const ush8 v10b = *(const ush8*)(tb + pp10*128 + (cb1 ^ ((pp10&7)<<4)));
            const ush8 v11b = *(const ush8*)(tb + pp11*128 + (cb1 ^ ((pp11&7)<<4)));
#pragma unroll
            for (int ci = 0; ci < 8; ++ci) {
                float v = w00*b2f(v00a[ci]) + w01*b2f(v01a[ci]) +
                          w10*b2f(v10a[ci]) + w11*b2f(v11a[ci]);
                a0[ci] = (short)f2b(v);
            }
#pragma unroll
            for (int ci = 0; ci < 8; ++ci) {
                float v = w00*b2f(v00b[ci]) + w01*b2f(v01b[ci]) +
                          w10*b2f(v10b[ci]) + w11*b2f(v11b[ci]);
                a1[ci] = (short)f2b(v);
            }
        } else {
            const bool vy0 = (unsigned)r0 < 256u, vy1 = (unsigned)r1 < 256u;
            const bool vx0 = (unsigned)c0 < 256u, vx1 = (unsigned)c1 < 256u;
            float W00 = w00, W01 = w01, W10 = w10, W11 = w11;
            int o00, o01, o10, o11;
            if (vy0 && vx0) o00 = r0*WW + c0; else { o00 = 0; W00 = 0.f; }
            if (vy0 && vx1) o01 = r0*WW + c1; else { o01 = 0; W01 = 0.f; }
            if (vy1 && vx0) o10 = r1*WW + c0; else { o10 = 0; W10 = 0.f; }
            if (vy1 && vx1) o11 = r1*WW + c1; else { o11 = 0; W11 = 0.f; }
            const float* pc0 = xb + (size_t)cA0 * HW;
#pragma unroll
            for (int ci = 0; ci < 8; ++ci) {
                float v = W00*pc0[o00] + W01*pc0[o01] + W10*pc0[o10] + W11*pc0[o11];
                pc0 += HW;
                a0[ci] = (short)f2b(v);
            }
            const float* pc1 = xb + (size_t)cA1 * HW;
#pragma unroll
            for (int ci = 0; ci < 8; ++ci) {
                float v = W00*pc1[o00] + W01*pc1[o01] + W10*pc1[o10] + W11*pc1[o11];
                pc1 += HW;
                a1[ci] = (short)f2b(v);
            }
        }

        // MFMA tap k: A-frags straight from registers
#pragma unroll
        for (int n = 0; n < 4; ++n)
            acc[n] = __builtin_amdgcn_mfma_f32_16x16x32_bf16(a0, bf0[n], acc[n], 0, 0, 0);
#pragma unroll
        for (int n = 0; n < 4; ++n)
            acc[n] = __builtin_amdgcn_mfma_f32_16x16x32_bf16(a1, bf1[n], acc[n], 0, 0, 0);
    }

    // ---- Epilogue: transpose via LDS (overlays tile) -> coalesced ReLU stores
    __syncthreads();
    float* ct = (float*)lds;    // [64 o][66]
#pragma unroll
    for (int n = 0; n < 4; ++n)
#pragma unroll
        for (int r = 0; r < 4; ++r)
            ct[(n*16 + lrow)*66 + wv*16 + lg*4 + r] = acc[n][r];
    __syncthreads();

    const size_t ob = (size_t)b*OO*HW + (size_t)h*WW + w0;
#pragma unroll
    for (int it = 0; it < 16; ++it) {
        int o = it*4 + wv;
        out[ob + (size_t)o*HW + lane] = fmaxf(ct[o*66 + lane], 0.f);
    }
}

extern "C" void kernel_launch(void* const* d_in, const int* in_sizes, int n_in,
                              void* d_out, int out_size, void* d_ws, size_t ws_size,
                              hipStream_t stream) {
    const float* x    = (const float*)d_in[0];
    const float* offw = (const float*)d_in[1];
    const float* offb = (const float*)d_in[2];
    const float* ampw = (const float*)d_in[3];
    const float* ampb = (const float*)d_in[4];
    const float* w3d  = (const float*)d_in[5];
    float* out = (float*)d_out;

    unsigned short* wA = (unsigned short*)d_ws;          // 18432 bf16
    unsigned short* wk = wA + 18432;                     // 36864 bf16

    k_prep<<<216, 256, 0, stream>>>(offw, ampw, w3d, wA, wk);
    k_fused<<<BB*HH*4, 256, 0, stream>>>(x, wA, wk, offb, ampb, out);
}

// Round 7
// 133.778 us; speedup vs baseline: 6.7961x; 1.1423x over previous
//
#include <hip/hip_runtime.h>
#include <hip/hip_bf16.h>
#include <math.h>

// Problem constants
#define BB 2
#define CC 64
#define HH 256
#define WW 256
#define OO 64
#define K2 9
#define HW 65536
#define CHW (CC*HW)

typedef __attribute__((ext_vector_type(8))) short sh8;
typedef __attribute__((ext_vector_type(4))) unsigned int ux4;
typedef __attribute__((ext_vector_type(2))) float f32x2;
typedef __attribute__((ext_vector_type(4))) float f32x4;

// Bijective XCD swizzle (nwg divisible by 8)
__device__ __forceinline__ int xcd_swz(int bid, int nwg) {
    const int per = nwg >> 3;
    return (bid & 7) * per + (bid >> 3);
}
__device__ __forceinline__ float b2f(unsigned short u) {
    unsigned int x = ((unsigned int)u) << 16;
    return __builtin_bit_cast(float, x);
}
__device__ __forceinline__ unsigned short f2b(float f) {
    __hip_bfloat16 h = __float2bfloat16(f);
    return __builtin_bit_cast(unsigned short, h);
}
// HW packed f32->2xbf16 (RNE), verified on gfx950 (guide T12)
__device__ __forceinline__ unsigned int cvtpk(float lo, float hi) {
    unsigned int r;
    asm("v_cvt_pk_bf16_f32 %0, %1, %2" : "=v"(r) : "v"(lo), "v"(hi));
    return r;
}
__device__ __forceinline__ f32x2 unpk_lohi(unsigned int d, unsigned int which_hi) {
    // returns {f32(lo16), f32(hi16)}
    f32x2 r;
    r.x = __builtin_bit_cast(float, d << 16);
    r.y = __builtin_bit_cast(float, d & 0xffff0000u);
    (void)which_hi;
    return r;
}

// wA: [32 ch][576 s'] bf16, s' = tap*64 + c (tap-major K order). rows 27..31 = 0.
// wk: [9 k][64 o][64 c] bf16.
__global__ __launch_bounds__(256) void k_prep(
    const float* __restrict__ offw, const float* __restrict__ ampw,
    const float* __restrict__ w3d,
    unsigned short* __restrict__ wA, unsigned short* __restrict__ wk)
{
    int i = blockIdx.x * 256 + threadIdx.x;   // grid 216 -> 55296 exact
    if (i < 18432) {
        int ch = i / 576, sp = i % 576;
        int tap = sp >> 6, c = sp & 63;
        float v = 0.f;
        if (ch < 18)      v = offw[ch*576 + c*9 + tap];
        else if (ch < 27) v = ampw[(ch-18)*576 + c*9 + tap];
        wA[i] = f2b(v);
    } else if (i < 55296) {
        int j = i - 18432;
        int k = j >> 12, rem = j & 4095;
        int o = rem >> 6, c = rem & 63;
        wk[j] = f2b(w3d[o*576 + c*9 + k]);
    }
}

// Fused kernel. Block = 256 thr = 4 waves, owns (b, h, 64-px quarter-row), all 64 o.
// Thread (lrow, lg) samples its own MFMA A-fragment -> no A LDS, no k-loop barriers.
__global__ __launch_bounds__(256, 3) void k_fused(
    const float* __restrict__ x, const unsigned short* __restrict__ wA,
    const unsigned short* __restrict__ wk,
    const float* __restrict__ offb, const float* __restrict__ ampb,
    float* __restrict__ out)
{
    // LDS map:
    //  tb  [0,43520)      : tile bf16, 340 planes (pp = rrel*68+ccrel) x 128B (64 c),
    //                       16B-slot XOR-swizzled by (pp&7)
    //  ot16[43520,47192)  : conv+bias out bf16 [27 ch][68]
    //  epilogue: ct f32 [64][66] overlays tb.
    __shared__ __attribute__((aligned(16))) unsigned char lds[47200];
    unsigned char* tb = lds;
    unsigned short* ot16 = (unsigned short*)(lds + 43520);

    const int tid = threadIdx.x;
    const int idx = xcd_swz(blockIdx.x, BB*HH*4);
    const int wq = idx & 3, h = (idx >> 2) & 255, b = idx >> 10;
    const int w0 = wq << 6;
    const int lane = tid & 63, wv = tid >> 6;
    const int lrow = lane & 15, lg = lane >> 4;

    const float* xb = x + (size_t)b * CHW;
    const int r0a = h - 2, c0a = w0 - 2;

    // ---- Phase 1: stage tile. Thread owns plane(s); 16 independent loads per
    // chunk batched before one wait; HW packed bf16 conversion.
    {
        auto stage_plane = [&](int pp) {
            const int rr = pp / 68;
            const int cc = pp - rr*68;
            const int ra = r0a + rr, ca = c0a + cc;
            const bool inb = ((unsigned)ra < 256u) && ((unsigned)ca < 256u);
            const float* ps = xb + ra*256 + ca;
            const int swz = (pp & 7) << 4;
#pragma unroll
            for (int ch = 0; ch < 64; ch += 16) {
                float v[16];
#pragma unroll
                for (int j = 0; j < 16; ++j)
                    v[j] = inb ? ps[(size_t)(ch + j) * HW] : 0.f;
                ux4 q0, q1;
                q0[0] = cvtpk(v[0],  v[1]);
                q0[1] = cvtpk(v[2],  v[3]);
                q0[2] = cvtpk(v[4],  v[5]);
                q0[3] = cvtpk(v[6],  v[7]);
                q1[0] = cvtpk(v[8],  v[9]);
                q1[1] = cvtpk(v[10], v[11]);
                q1[2] = cvtpk(v[12], v[13]);
                q1[3] = cvtpk(v[14], v[15]);
                *(ux4*)(tb + pp*128 + ((ch*2     ) ^ swz)) = q0;
                *(ux4*)(tb + pp*128 + ((ch*2 + 16) ^ swz)) = q1;
            }
        };
        stage_plane(tid);
        if (tid < 340 - 256) stage_plane(tid + 256);
    }
    __syncthreads();

    // ---- Phase 2: offset/amp conv via MFMA. D[m=ch(32)][n=px(16/wave)], K=576.
    {
        f32x4 oacc0 = {0.f,0.f,0.f,0.f}, oacc1 = {0.f,0.f,0.f,0.f};
        const int pxl = wv*16 + lrow;
#pragma unroll
        for (int ks = 0; ks < 18; ++ks) {
            const int sbase = ks*32 + lg*8;
            const int tap = sbase >> 6;
            const int cb  = sbase & 63;
            const int ky = tap / 3, kx = tap - ky*3;
            const int pp = (ky + 1)*68 + pxl + kx + 1;
            const sh8 bf = *(const sh8*)(tb + pp*128 + ((2*cb) ^ ((pp & 7) << 4)));
            const sh8 a0 = *(const sh8*)(wA + (      lrow)*576 + sbase);
            const sh8 a1 = *(const sh8*)(wA + (16 + lrow)*576 + sbase);
            oacc0 = __builtin_amdgcn_mfma_f32_16x16x32_bf16(a0, bf, oacc0, 0, 0, 0);
            oacc1 = __builtin_amdgcn_mfma_f32_16x16x32_bf16(a1, bf, oacc1, 0, 0, 0);
        }
#pragma unroll
        for (int r = 0; r < 4; ++r) {
            int ch0 = lg*4 + r;
            ot16[ch0*68 + pxl] = f2b(oacc0[r] + offb[ch0]);
            int ch1 = 16 + lg*4 + r;
            if (ch1 < 27) {
                float bias = (ch1 < 18) ? offb[ch1] : ampb[ch1 - 18];
                ot16[ch1*68 + pxl] = f2b(oacc1[r] + bias);
            }
        }
    }
    __syncthreads();

    // ---- Phase 3: barrier-free K-loop over 9 taps.
    f32x4 acc[4];
#pragma unroll
    for (int n = 0; n < 4; ++n) acc[n] = (f32x4){0.f, 0.f, 0.f, 0.f};

    const int px = wv*16 + lrow;          // this thread's A-row pixel
    const int cA0 = lg*8;                 // kk=0 c-chunk base (fallback path)
    const int cA1 = 32 + lg*8;            // kk=1 c-chunk base
    const int cb0 = lg*16;                // byte offsets within a 128B plane
    const int cb1 = 64 + lg*16;

#pragma unroll 3
    for (int k = 0; k < K2; ++k) {
        // B-fragments for tap k, directly from global (L2-resident 8KB slice)
        sh8 bf0[4], bf1[4];
        {
            const unsigned short* wb = wk + (size_t)k*4096 + lg*8;
#pragma unroll
            for (int n = 0; n < 4; ++n) {
                bf0[n] = *(const sh8*)(wb + (n*16 + lrow)*64);
                bf1[n] = *(const sh8*)(wb + (n*16 + lrow)*64 + 32);
            }
        }

        // sampling params for (px, tap k)
        const int ky = k / 3, kx = k - ky*3;
        const float oy = b2f(ot16[(2*k  )*68 + px]);
        const float ox = b2f(ot16[(2*k+1)*68 + px]);
        const float az = b2f(ot16[(18+k )*68 + px]);
        float yy = (float)(h + ky) + oy;
        float xx = (float)(w0 + px + kx) + ox;
        yy = fminf(fmaxf(yy, 0.f), 257.f);
        xx = fminf(fmaxf(xx, 0.f), 257.f);
        const float aa = 1.f / (1.f + __expf(-az));

        const float y0f = floorf(yy), x0f = floorf(xx);
        const float y1f = fminf(y0f + 1.f, 257.f);
        const float x1f = fminf(x0f + 1.f, 257.f);
        const float ay = yy - y0f, by = y1f - yy;
        const float ax = xx - x0f, bx = x1f - xx;
        const int r0 = (int)y0f - 1, r1 = (int)y1f - 1;
        const int c0 = (int)x0f - 1, c1 = (int)x1f - 1;
        const int rr0 = r0 - (h - 2), rr1 = r1 - (h - 2);
        const int cc0 = c0 - (w0 - 2), cc1 = c1 - (w0 - 2);
        const float w00 = by*bx*aa, w01 = by*ax*aa, w10 = ay*bx*aa, w11 = ay*ax*aa;

        union { ux4 q; sh8 s; } A0, A1;
        const bool ok = ((unsigned)rr0 <= 4u) && ((unsigned)rr1 <= 4u) &&
                        ((unsigned)cc0 <= 67u) && ((unsigned)cc1 <= 67u);
        if (ok) {
            const int pp00 = rr0*68 + cc0, pp01 = rr0*68 + cc1;
            const int pp10 = rr1*68 + cc0, pp11 = rr1*68 + cc1;
            const int s00 = (pp00 & 7) << 4, s01 = (pp01 & 7) << 4;
            const int s10 = (pp10 & 7) << 4, s11 = (pp11 & 7) << 4;
            const f32x2 W00 = {w00, w00}, W01 = {w01, w01};
            const f32x2 W10 = {w10, w10}, W11 = {w11, w11};

            auto bilerp8 = [&](int off) -> ux4 {
                const ux4 d00 = *(const ux4*)(tb + pp00*128 + (off ^ s00));
                const ux4 d01 = *(const ux4*)(tb + pp01*128 + (off ^ s01));
                const ux4 d10 = *(const ux4*)(tb + pp10*128 + (off ^ s10));
                const ux4 d11 = *(const ux4*)(tb + pp11*128 + (off ^ s11));
                ux4 r;
#pragma unroll
                for (int j = 0; j < 4; ++j) {
                    const f32x2 p00 = unpk_lohi(d00[j], 0);
                    const f32x2 p01 = unpk_lohi(d01[j], 0);
                    const f32x2 p10 = unpk_lohi(d10[j], 0);
                    const f32x2 p11 = unpk_lohi(d11[j], 0);
                    f32x2 t = p00 * W00;
                    t = __builtin_elementwise_fma(p01, W01, t);
                    t = __builtin_elementwise_fma(p10, W10, t);
                    t = __builtin_elementwise_fma(p11, W11, t);
                    r[j] = cvtpk(t.x, t.y);
                }
                return r;
            };
            A0.q = bilerp8(cb0);
            A1.q = bilerp8(cb1);
        } else {
            const bool vy0 = (unsigned)r0 < 256u, vy1 = (unsigned)r1 < 256u;
            const bool vx0 = (unsigned)c0 < 256u, vx1 = (unsigned)c1 < 256u;
            float W00 = w00, W01 = w01, W10 = w10, W11 = w11;
            int o00, o01, o10, o11;
            if (vy0 && vx0) o00 = r0*WW + c0; else { o00 = 0; W00 = 0.f; }
            if (vy0 && vx1) o01 = r0*WW + c1; else { o01 = 0; W01 = 0.f; }
            if (vy1 && vx0) o10 = r1*WW + c0; else { o10 = 0; W10 = 0.f; }
            if (vy1 && vx1) o11 = r1*WW + c1; else { o11 = 0; W11 = 0.f; }
            const float* pc0 = xb + (size_t)cA0 * HW;
            const float* pc1 = xb + (size_t)cA1 * HW;
#pragma unroll
            for (int jj = 0; jj < 4; ++jj) {
                float va = W00*pc0[o00] + W01*pc0[o01] + W10*pc0[o10] + W11*pc0[o11];
                pc0 += HW;
                float vb = W00*pc0[o00] + W01*pc0[o01] + W10*pc0[o10] + W11*pc0[o11];
                pc0 += HW;
                A0.q[jj] = cvtpk(va, vb);
                float vc = W00*pc1[o00] + W01*pc1[o01] + W10*pc1[o10] + W11*pc1[o11];
                pc1 += HW;
                float vd = W00*pc1[o00] + W01*pc1[o01] + W10*pc1[o10] + W11*pc1[o11];
                pc1 += HW;
                A1.q[jj] = cvtpk(vc, vd);
            }
        }

        // MFMA tap k: A-frags straight from registers
#pragma unroll
        for (int n = 0; n < 4; ++n)
            acc[n] = __builtin_amdgcn_mfma_f32_16x16x32_bf16(A0.s, bf0[n], acc[n], 0, 0, 0);
#pragma unroll
        for (int n = 0; n < 4; ++n)
            acc[n] = __builtin_amdgcn_mfma_f32_16x16x32_bf16(A1.s, bf1[n], acc[n], 0, 0, 0);
    }

    // ---- Epilogue: transpose via LDS (overlays tile) -> coalesced ReLU stores
    __syncthreads();
    float* ct = (float*)lds;    // [64 o][66]
#pragma unroll
    for (int n = 0; n < 4; ++n)
#pragma unroll
        for (int r = 0; r < 4; ++r)
            ct[(n*16 + lrow)*66 + wv*16 + lg*4 + r] = acc[n][r];
    __syncthreads();

    const size_t ob = (size_t)b*OO*HW + (size_t)h*WW + w0;
#pragma unroll
    for (int it = 0; it < 16; ++it) {
        int o = it*4 + wv;
        out[ob + (size_t)o*HW + lane] = fmaxf(ct[o*66 + lane], 0.f);
    }
}

extern "C" void kernel_launch(void* const* d_in, const int* in_sizes, int n_in,
                              void* d_out, int out_size, void* d_ws, size_t ws_size,
                              hipStream_t stream) {
    const float* x    = (const float*)d_in[0];
    const float* offw = (const float*)d_in[1];
    const float* offb = (const float*)d_in[2];
    const float* ampw = (const float*)d_in[3];
    const float* ampb = (const float*)d_in[4];
    const float* w3d  = (const float*)d_in[5];
    float* out = (float*)d_out;

    unsigned short* wA = (unsigned short*)d_ws;          // 18432 bf16
    unsigned short* wk = wA + 18432;                     // 36864 bf16

    k_prep<<<216, 256, 0, stream>>>(offw, ampw, w3d, wA, wk);
    k_fused<<<BB*HH*4, 256, 0, stream>>>(x, wA, wk, offb, ampb, out);
}

// Round 9
// 132.046 us; speedup vs baseline: 6.8852x; 1.0131x over previous
//
#include <hip/hip_runtime.h>
#include <hip/hip_bf16.h>
#include <math.h>

// Problem constants
#define BB 2
#define CC 64
#define HH 256
#define WW 256
#define OO 64
#define K2 9
#define HW 65536
#define CHW (CC*HW)

typedef _Float16 h8 __attribute__((ext_vector_type(8)));
typedef __fp16 fp16x2 __attribute__((ext_vector_type(2)));
typedef __attribute__((ext_vector_type(4))) unsigned int ux4;
typedef __attribute__((ext_vector_type(4))) float f32x4;

// Bijective XCD swizzle (nwg divisible by 8)
__device__ __forceinline__ int xcd_swz(int bid, int nwg) {
    const int per = nwg >> 3;
    return (bid & 7) * per + (bid >> 3);
}
__device__ __forceinline__ unsigned short f2h(float f) {
    _Float16 h = (_Float16)f;
    return __builtin_bit_cast(unsigned short, h);
}
__device__ __forceinline__ unsigned int pkrtz(float lo, float hi) {
    fp16x2 p = __builtin_amdgcn_cvt_pkrtz(lo, hi);
    return __builtin_bit_cast(unsigned int, p);
}
__device__ __forceinline__ h8 splat8(float f) {
    _Float16 h = (_Float16)f;
    h8 r = {h, h, h, h, h, h, h, h};
    return r;
}

// wA: [32 ch][576 s'] fp16, s' = tap*64 + c (tap-major K order). rows 27..31 = 0.
// wk: [9 k][64 o][64 c] fp16.
__global__ __launch_bounds__(256) void k_prep(
    const float* __restrict__ offw, const float* __restrict__ ampw,
    const float* __restrict__ w3d,
    unsigned short* __restrict__ wA, unsigned short* __restrict__ wk)
{
    int i = blockIdx.x * 256 + threadIdx.x;   // grid 216 -> 55296 exact
    if (i < 18432) {
        int ch = i / 576, sp = i % 576;
        int tap = sp >> 6, c = sp & 63;
        float v = 0.f;
        if (ch < 18)      v = offw[ch*576 + c*9 + tap];
        else if (ch < 27) v = ampw[(ch-18)*576 + c*9 + tap];
        wA[i] = f2h(v);
    } else if (i < 55296) {
        int j = i - 18432;
        int k = j >> 12, rem = j & 4095;
        int o = rem >> 6, c = rem & 63;
        wk[j] = f2h(w3d[o*576 + c*9 + k]);
    }
}

// Fused kernel. Block = 256 thr = 4 waves, owns (b, h, 64-px quarter-row), all 64 o.
// Thread (lrow, lg) samples its own MFMA A-fragment; all matrix math in fp16
// (packed v_pk_fma_f16 bilerp -> mfma_f32_16x16x32_f16), f32 accumulate.
__global__ __launch_bounds__(256, 3) void k_fused(
    const float* __restrict__ x, const unsigned short* __restrict__ wA,
    const unsigned short* __restrict__ wk,
    const float* __restrict__ offb, const float* __restrict__ ampb,
    float* __restrict__ out)
{
    // LDS map:
    //  tb  [0,43520)      : tile fp16, 340 planes (pp = rrel*68+ccrel) x 128B (64 c),
    //                       16B-slot XOR-swizzled by (pp&7)
    //  ot16[43520,47192)  : conv+bias out fp16 [27 ch][68]
    //  epilogue: ct f32 [64][66] overlays tb.
    __shared__ __attribute__((aligned(16))) unsigned char lds[47200];
    unsigned char* tb = lds;
    _Float16* ot16 = (_Float16*)(lds + 43520);

    const int tid = threadIdx.x;
    const int idx = xcd_swz(blockIdx.x, BB*HH*4);
    const int wq = idx & 3, h = (idx >> 2) & 255, b = idx >> 10;
    const int w0 = wq << 6;
    const int lane = tid & 63, wv = tid >> 6;
    const int lrow = lane & 15, lg = lane >> 4;

    const float* xb = x + (size_t)b * CHW;
    const int r0a = h - 2, c0a = w0 - 2;

    // ---- Phase 1: stage tile. Thread owns plane(s); all 64 channel loads of a
    // plane issued before use; packed fp16 conversion (cvt_pkrtz).
    {
        auto stage_plane = [&](int pp) {
            const int rr = pp / 68;
            const int cc = pp - rr*68;
            const int ra = r0a + rr, ca = c0a + cc;
            const bool inb = ((unsigned)ra < 256u) && ((unsigned)ca < 256u);
            const float* ps = xb + ra*256 + ca;
            const int swz = (pp & 7) << 4;
            float v[64];
#pragma unroll
            for (int j = 0; j < 64; ++j)
                v[j] = inb ? ps[(size_t)j * HW] : 0.f;
#pragma unroll
            for (int s = 0; s < 8; ++s) {
                ux4 w;
#pragma unroll
                for (int t = 0; t < 4; ++t)
                    w[t] = pkrtz(v[s*8 + 2*t], v[s*8 + 2*t + 1]);
                *(ux4*)(tb + pp*128 + ((s*16) ^ swz)) = w;
            }
        };
        stage_plane(tid);
        if (tid < 340 - 256) stage_plane(tid + 256);
    }
    __syncthreads();

    // ---- Phase 2: offset/amp conv via MFMA (fp16). D[m=ch(32)][n=px], K=576.
    {
        f32x4 oacc0 = {0.f,0.f,0.f,0.f}, oacc1 = {0.f,0.f,0.f,0.f};
        const int pxl = wv*16 + lrow;
#pragma unroll
        for (int ks = 0; ks < 18; ++ks) {
            const int sbase = ks*32 + lg*8;
            const int tap = sbase >> 6;
            const int cb  = sbase & 63;
            const int ky = tap / 3, kx = tap - ky*3;
            const int pp = (ky + 1)*68 + pxl + kx + 1;
            const h8 bf = *(const h8*)(tb + pp*128 + ((2*cb) ^ ((pp & 7) << 4)));
            const h8 a0 = *(const h8*)(wA + (      lrow)*576 + sbase);
            const h8 a1 = *(const h8*)(wA + (16 + lrow)*576 + sbase);
            oacc0 = __builtin_amdgcn_mfma_f32_16x16x32_f16(a0, bf, oacc0, 0, 0, 0);
            oacc1 = __builtin_amdgcn_mfma_f32_16x16x32_f16(a1, bf, oacc1, 0, 0, 0);
        }
#pragma unroll
        for (int r = 0; r < 4; ++r) {
            int ch0 = lg*4 + r;
            ot16[ch0*68 + pxl] = (_Float16)(oacc0[r] + offb[ch0]);
            int ch1 = 16 + lg*4 + r;
            if (ch1 < 27) {
                float bias = (ch1 < 18) ? offb[ch1] : ampb[ch1 - 18];
                ot16[ch1*68 + pxl] = (_Float16)(oacc1[r] + bias);
            }
        }
    }
    __syncthreads();

    // ---- Phase 3: barrier-free K-loop over 9 taps.
    f32x4 acc[4];
#pragma unroll
    for (int n = 0; n < 4; ++n) acc[n] = (f32x4){0.f, 0.f, 0.f, 0.f};

    const int px = wv*16 + lrow;          // this thread's A-row pixel
    const int cA0 = lg*8;                 // kk=0 c-chunk base (fallback path)
    const int cA1 = 32 + lg*8;            // kk=1 c-chunk base
    const int cb0 = lg*16;                // byte offsets within a 128B plane
    const int cb1 = 64 + lg*16;

#pragma unroll 3
    for (int k = 0; k < K2; ++k) {
        // B-fragments for tap k, directly from global (L2-resident 8KB slice)
        h8 bf0[4], bf1[4];
        {
            const unsigned short* wb = wk + (size_t)k*4096 + lg*8;
#pragma unroll
            for (int n = 0; n < 4; ++n) {
                bf0[n] = *(const h8*)(wb + (n*16 + lrow)*64);
                bf1[n] = *(const h8*)(wb + (n*16 + lrow)*64 + 32);
            }
        }

        // sampling params for (px, tap k)
        const int ky = k / 3, kx = k - ky*3;
        const float oy = (float)ot16[(2*k  )*68 + px];
        const float ox = (float)ot16[(2*k+1)*68 + px];
        const float az = (float)ot16[(18+k )*68 + px];
        float yy = (float)(h + ky) + oy;
        float xx = (float)(w0 + px + kx) + ox;
        yy = fminf(fmaxf(yy, 0.f), 257.f);
        xx = fminf(fmaxf(xx, 0.f), 257.f);
        const float aa = 1.f / (1.f + __expf(-az));

        const float y0f = floorf(yy), x0f = floorf(xx);
        const float y1f = fminf(y0f + 1.f, 257.f);
        const float x1f = fminf(x0f + 1.f, 257.f);
        const float ay = yy - y0f, by = y1f - yy;
        const float ax = xx - x0f, bx = x1f - xx;
        const int r0 = (int)y0f - 1, r1 = (int)y1f - 1;
        const int c0 = (int)x0f - 1, c1 = (int)x1f - 1;
        const int rr0 = r0 - (h - 2), rr1 = r1 - (h - 2);
        const int cc0 = c0 - (w0 - 2), cc1 = c1 - (w0 - 2);
        const float w00 = by*bx*aa, w01 = by*ax*aa, w10 = ay*bx*aa, w11 = ay*ax*aa;

        h8 A0, A1;
        const bool ok = ((unsigned)rr0 <= 4u) && ((unsigned)rr1 <= 4u) &&
                        ((unsigned)cc0 <= 67u) && ((unsigned)cc1 <= 67u);
        if (ok) {
            const int pp00 = rr0*68 + cc0, pp01 = rr0*68 + cc1;
            const int pp10 = rr1*68 + cc0, pp11 = rr1*68 + cc1;
            const int s00 = (pp00 & 7) << 4, s01 = (pp01 & 7) << 4;
            const int s10 = (pp10 & 7) << 4, s11 = (pp11 & 7) << 4;
            const h8 Wb00 = splat8(w00), Wb01 = splat8(w01);
            const h8 Wb10 = splat8(w10), Wb11 = splat8(w11);

            auto bilerp8 = [&](int off) -> h8 {
                const h8 d00 = *(const h8*)(tb + pp00*128 + (off ^ s00));
                const h8 d01 = *(const h8*)(tb + pp01*128 + (off ^ s01));
                const h8 d10 = *(const h8*)(tb + pp10*128 + (off ^ s10));
                const h8 d11 = *(const h8*)(tb + pp11*128 + (off ^ s11));
                h8 t = d00 * Wb00;
                t = __builtin_elementwise_fma(d01, Wb01, t);
                t = __builtin_elementwise_fma(d10, Wb10, t);
                t = __builtin_elementwise_fma(d11, Wb11, t);
                return t;
            };
            A0 = bilerp8(cb0);
            A1 = bilerp8(cb1);
        } else {
            const bool vy0 = (unsigned)r0 < 256u, vy1 = (unsigned)r1 < 256u;
            const bool vx0 = (unsigned)c0 < 256u, vx1 = (unsigned)c1 < 256u;
            float W00 = w00, W01 = w01, W10 = w10, W11 = w11;
            int o00, o01, o10, o11;
            if (vy0 && vx0) o00 = r0*WW + c0; else { o00 = 0; W00 = 0.f; }
            if (vy0 && vx1) o01 = r0*WW + c1; else { o01 = 0; W01 = 0.f; }
            if (vy1 && vx0) o10 = r1*WW + c0; else { o10 = 0; W10 = 0.f; }
            if (vy1 && vx1) o11 = r1*WW + c1; else { o11 = 0; W11 = 0.f; }
            const float* pc0 = xb + (size_t)cA0 * HW;
            const float* pc1 = xb + (size_t)cA1 * HW;
#pragma unroll
            for (int jj = 0; jj < 8; ++jj) {
                float va = W00*pc0[o00] + W01*pc0[o01] + W10*pc0[o10] + W11*pc0[o11];
                pc0 += HW;
                A0[jj] = (_Float16)va;
                float vb = W00*pc1[o00] + W01*pc1[o01] + W10*pc1[o10] + W11*pc1[o11];
                pc1 += HW;
                A1[jj] = (_Float16)vb;
            }
        }

        // MFMA tap k: A-frags straight from registers
#pragma unroll
        for (int n = 0; n < 4; ++n)
            acc[n] = __builtin_amdgcn_mfma_f32_16x16x32_f16(A0, bf0[n], acc[n], 0, 0, 0);
#pragma unroll
        for (int n = 0; n < 4; ++n)
            acc[n] = __builtin_amdgcn_mfma_f32_16x16x32_f16(A1, bf1[n], acc[n], 0, 0, 0);
    }

    // ---- Epilogue: transpose via LDS (overlays tile) -> coalesced ReLU stores
    __syncthreads();
    float* ct = (float*)lds;    // [64 o][66]
#pragma unroll
    for (int n = 0; n < 4; ++n)
#pragma unroll
        for (int r = 0; r < 4; ++r)
            ct[(n*16 + lrow)*66 + wv*16 + lg*4 + r] = acc[n][r];
    __syncthreads();

    const size_t ob = (size_t)b*OO*HW + (size_t)h*WW + w0;
#pragma unroll
    for (int it = 0; it < 16; ++it) {
        int o = it*4 + wv;
        out[ob + (size_t)o*HW + lane] = fmaxf(ct[o*66 + lane], 0.f);
    }
}

extern "C" void kernel_launch(void* const* d_in, const int* in_sizes, int n_in,
                              void* d_out, int out_size, void* d_ws, size_t ws_size,
                              hipStream_t stream) {
    const float* x    = (const float*)d_in[0];
    const float* offw = (const float*)d_in[1];
    const float* offb = (const float*)d_in[2];
    const float* ampw = (const float*)d_in[3];
    const float* ampb = (const float*)d_in[4];
    const float* w3d  = (const float*)d_in[5];
    float* out = (float*)d_out;

    unsigned short* wA = (unsigned short*)d_ws;          // 18432 fp16
    unsigned short* wk = wA + 18432;                     // 36864 fp16

    k_prep<<<216, 256, 0, stream>>>(offw, ampw, w3d, wA, wk);
    k_fused<<<BB*HH*4, 256, 0, stream>>>(x, wA, wk, offb, ampb, out);
}